// Round 1
// baseline (6780.881 us; speedup 1.0000x reference)
//
#include <hip/hip_runtime.h>
#include <stdint.h>

#define BB 32
#define LL 1024
#define NW 512
#define HH 768
#define HID 384
#define G4 1536   // 4*HID
#define EE 4
#define DLL 128
#define GIN 896   // H+DL
#define CWG 24    // column-group WGs per direction
#define COLS 16   // h-cols per WG

typedef __attribute__((ext_vector_type(8))) short short8;
typedef __attribute__((ext_vector_type(4))) float f32x4;

__device__ __forceinline__ float bf2f(short s){
  union { unsigned int u; float f; } v; v.u = ((unsigned int)(unsigned short)s) << 16; return v.f;
}
__device__ __forceinline__ short f2bf(float f){
  union { float f; unsigned int u; } v; v.f = f;
  unsigned int r = v.u + 0x7fffu + ((v.u >> 16) & 1u);
  return (short)(r >> 16);
}
__device__ __forceinline__ float sigm(float x){ return 1.f / (1.f + __expf(-x)); }

// ---------------- zero flags ----------------
__global__ void k_zero(int* flags){
  int i = blockIdx.x * 256 + threadIdx.x;
  if (i < 2 * NW) flags[i] = 0;
}

// ---------------- f32 -> bf16 convert ----------------
__global__ void k_f2bf(const float* in, short* out, int n){
  int i = blockIdx.x * blockDim.x + threadIdx.x;
  int st = gridDim.x * blockDim.x;
  for (; i < n; i += st) out[i] = f2bf(in[i]);
}

// ---------------- segment mean pooling ----------------
__global__ __launch_bounds__(256) void k_segmean(const float* __restrict__ tok,
                                                 const int* __restrict__ wmap,
                                                 short* __restrict__ we_bf){
  int blk = blockIdx.x;
  int b = blk >> 9;          // / NW
  int w = blk & 511;
  const int* m = wmap + b * LL;
  int lo = 0, hi = LL;
  while (lo < hi){ int mid = (lo + hi) >> 1; if (m[mid] < w) lo = mid + 1; else hi = mid; }
  int s = lo;
  int lo2 = s, hi2 = LL;
  while (lo2 < hi2){ int mid = (lo2 + hi2) >> 1; if (m[mid] <= w) lo2 = mid + 1; else hi2 = mid; }
  int e = lo2;
  float cnt = (float)(e - s);
  float denom = fmaxf(cnt, 1.f);
  for (int j = threadIdx.x; j < HH; j += 256){
    float acc = 0.f;
    for (int r = s; r < e; ++r) acc += tok[((size_t)b * LL + r) * HH + j];
    we_bf[((size_t)b * NW + w) * HH + j] = f2bf(acc / denom);
  }
}

// ---------------- GEMM: C[M,N] = A[M,K](bf16) * W[N,K]^T(bf16) + b1[n] + b2[n] ----------------
__global__ __launch_bounds__(256) void k_gemm_bt(const short* __restrict__ Abf,
                                                 const short* __restrict__ Wbf,
                                                 const float* __restrict__ b1,
                                                 const float* __restrict__ b2,
                                                 float* __restrict__ Cf,
                                                 int M, int N, int K){
  __shared__ __attribute__((aligned(16))) short As[128 * 32];
  __shared__ __attribute__((aligned(16))) short Bs[128 * 32];
  int ntiles = N >> 7;
  int m0 = (blockIdx.x / ntiles) << 7;
  int n0 = (blockIdx.x % ntiles) << 7;
  int tid = threadIdx.x, lane = tid & 63, wv = tid >> 6;
  int wm = (wv >> 1) << 6, wn = (wv & 1) << 6;
  f32x4 acc[4][4] = {};
  for (int kk = 0; kk < K; kk += 32){
#pragma unroll
    for (int q = 0; q < 2; ++q){
      int e = (q * 256 + tid) * 8;
      int row = e >> 5, col = e & 31;
      *(short8*)(As + e) = *(const short8*)(Abf + (size_t)(m0 + row) * K + kk + col);
      *(short8*)(Bs + e) = *(const short8*)(Wbf + (size_t)(n0 + row) * K + kk + col);
    }
    __syncthreads();
    short8 af[4], bfr[4];
#pragma unroll
    for (int x = 0; x < 4; ++x){
      af[x]  = *(const short8*)(As + (wm + x * 16 + (lane & 15)) * 32 + ((lane >> 4) << 3));
      bfr[x] = *(const short8*)(Bs + (wn + x * 16 + (lane & 15)) * 32 + ((lane >> 4) << 3));
    }
#pragma unroll
    for (int x = 0; x < 4; ++x)
#pragma unroll
      for (int y = 0; y < 4; ++y)
        acc[x][y] = __builtin_amdgcn_mfma_f32_16x16x32_bf16(af[x], bfr[y], acc[x][y], 0, 0, 0);
    __syncthreads();
  }
#pragma unroll
  for (int x = 0; x < 4; ++x)
#pragma unroll
    for (int y = 0; y < 4; ++y)
#pragma unroll
      for (int i = 0; i < 4; ++i){
        int mm = m0 + wm + x * 16 + ((lane >> 4) << 2) + i;
        int nn = n0 + wn + y * 16 + (lane & 15);
        Cf[(size_t)mm * N + nn] = acc[x][y][i] + b1[nn] + b2[nn];
      }
}

// ---------------- BiLSTM: persistent, flag-synced, Whh resident in VGPRs ----------------
__global__ __launch_bounds__(256) void k_lstm(const float* __restrict__ xg_f,
                                              const float* __restrict__ xg_b,
                                              const short* __restrict__ whh_f,
                                              const short* __restrict__ whh_b,
                                              short* __restrict__ hbuf,
                                              short* __restrict__ hcat,
                                              int* __restrict__ flags){
  int bx = blockIdx.x;
  int dir = bx / CWG;
  int cg  = bx % CWG;
  int tid = threadIdx.x, lane = tid & 63, wv = tid >> 6;   // wv = gate index (i,f,g,o)
  const float* xg  = dir ? xg_b : xg_f;
  const short* whh = dir ? whh_b : whh_f;
  int jbase = wv * HID + cg * COLS;   // gate-row base for this wave

  // resident B fragments: Whh rows [jbase .. jbase+16), K=384 -> 12 k-steps
  short8 bfrag[12];
  {
    const short* wr = whh + (size_t)(jbase + (lane & 15)) * HID + ((lane >> 4) << 3);
#pragma unroll
    for (int ks = 0; ks < 12; ++ks) bfrag[ks] = *(const short8*)(wr + ks * 32);
  }

  __shared__ float pre[4][BB][COLS];   // gate preacts exchange, 8 KB
  float c0 = 0.f, c1 = 0.f;            // cell state for this thread's 2 (b,col) slots
  int idx0 = tid * 2;
  int eb = idx0 >> 4, ec = idx0 & 15;  // elementwise (b, even col)
  int* flg = flags + dir * NW;
  short* hb0 = hbuf + (size_t)dir * 2 * BB * HID;

  for (int t = 0; t < NW; ++t){
    int t_act = dir ? (NW - 1 - t) : t;
    // prefetch xg (independent of h) — overlaps the flag wait
    float xgv[8];
#pragma unroll
    for (int mt = 0; mt < 2; ++mt)
#pragma unroll
      for (int i = 0; i < 4; ++i){
        int bb = mt * 16 + ((lane >> 4) << 2) + i;
        xgv[mt * 4 + i] = xg[((size_t)bb * NW + t_act) * G4 + jbase + (lane & 15)];
      }
    f32x4 acc0 = {}, acc1 = {};
    if (t > 0){
      while (__hip_atomic_load(&flg[t - 1], __ATOMIC_ACQUIRE, __HIP_MEMORY_SCOPE_AGENT) < CWG)
        __builtin_amdgcn_s_sleep(1);
      const short* hp = hb0 + ((t - 1) & 1) * BB * HID;
      const short* ha = hp + (size_t)(lane & 15) * HID + ((lane >> 4) << 3);
#pragma unroll
      for (int ks = 0; ks < 12; ++ks){
        short8 a0 = *(const short8*)(ha + ks * 32);
        short8 a1 = *(const short8*)(ha + 16 * HID + ks * 32);
        acc0 = __builtin_amdgcn_mfma_f32_16x16x32_bf16(a0, bfrag[ks], acc0, 0, 0, 0);
        acc1 = __builtin_amdgcn_mfma_f32_16x16x32_bf16(a1, bfrag[ks], acc1, 0, 0, 0);
      }
    }
#pragma unroll
    for (int i = 0; i < 4; ++i){
      int b0 = ((lane >> 4) << 2) + i;
      pre[wv][b0][lane & 15]      = acc0[i] + xgv[i];
      pre[wv][b0 + 16][lane & 15] = acc1[i] + xgv[4 + i];
    }
    __syncthreads();
    // elementwise LSTM cell for slots (idx0, idx0+1): same b, cols (ec, ec+1)
    short* hw = hb0 + (t & 1) * BB * HID;
    float h0, h1;
    {
      float gi = pre[0][eb][ec], gf = pre[1][eb][ec], gg = pre[2][eb][ec], go = pre[3][eb][ec];
      c0 = sigm(gf) * c0 + sigm(gi) * tanhf(gg);
      h0 = sigm(go) * tanhf(c0);
    }
    {
      float gi = pre[0][eb][ec + 1], gf = pre[1][eb][ec + 1], gg = pre[2][eb][ec + 1], go = pre[3][eb][ec + 1];
      c1 = sigm(gf) * c1 + sigm(gi) * tanhf(gg);
      h1 = sigm(go) * tanhf(c1);
    }
    unsigned int packed = (unsigned int)(unsigned short)f2bf(h0) |
                          ((unsigned int)(unsigned short)f2bf(h1) << 16);
    *(unsigned int*)(hw + eb * HID + cg * COLS + ec) = packed;
    *(unsigned int*)(hcat + ((size_t)eb * NW + t_act) * HH + dir * HID + cg * COLS + ec) = packed;
    __threadfence();
    __syncthreads();
    if (tid == 0) __hip_atomic_fetch_add(&flg[t], 1, __ATOMIC_RELEASE, __HIP_MEMORY_SCOPE_AGENT);
  }
}

// ---------------- gate MLP + softmax (per batch row) ----------------
__global__ __launch_bounds__(256) void k_gate(const float* __restrict__ tok,
                                              const int* __restrict__ lids,
                                              const float* __restrict__ ltab,
                                              const float* __restrict__ W1,
                                              const float* __restrict__ b1v,
                                              const float* __restrict__ W2,
                                              const float* __restrict__ b2v,
                                              float* __restrict__ gate){
  __shared__ float gin[GIN];
  __shared__ float hid[HH];
  __shared__ float pr[EE];
  int b = blockIdx.x, tid = threadIdx.x;
  int lid = lids[b];
  for (int i = tid; i < GIN; i += 256)
    gin[i] = (i < HH) ? tok[(size_t)b * LL * HH + i] : ltab[lid * DLL + (i - HH)];
  __syncthreads();
  for (int j = tid; j < HH; j += 256){
    float a = b1v[j];
    const float* wr = W1 + (size_t)j * GIN;
    for (int k = 0; k < GIN; ++k) a += gin[k] * wr[k];
    hid[j] = fmaxf(a, 0.f);
  }
  __syncthreads();
  int wv = tid >> 6, lane = tid & 63;
  if (wv < EE){
    float p = 0.f;
    for (int k = lane; k < HH; k += 64) p += hid[k] * W2[wv * HH + k];
#pragma unroll
    for (int off = 32; off; off >>= 1) p += __shfl_down(p, off);
    if (lane == 0) pr[wv] = p + b2v[wv];
  }
  __syncthreads();
  if (tid == 0){
    float mx = fmaxf(fmaxf(pr[0], pr[1]), fmaxf(pr[2], pr[3]));
    float s = 0.f, ex[EE];
    for (int e2 = 0; e2 < EE; ++e2){ ex[e2] = __expf(pr[e2] - mx); s += ex[e2]; }
    for (int e2 = 0; e2 < EE; ++e2) gate[b * EE + e2] = ex[e2] / s;
  }
}

// ---------------- head precompute: A = headW @ proj_W, c = headW.proj_b + head_b ----------------
__global__ __launch_bounds__(256) void k_headpre(const float* __restrict__ efW,
                                                 const float* __restrict__ efb,
                                                 const float* __restrict__ edW,
                                                 const float* __restrict__ edb,
                                                 const float* __restrict__ projW,
                                                 const float* __restrict__ projb,
                                                 float* __restrict__ Acomb,
                                                 float* __restrict__ Ccomb){
  int head = blockIdx.x >> 2, e2 = blockIdx.x & 3, tid = threadIdx.x;
  const float* Wv = head ? edW : efW;
  const float* bv = head ? edb : efb;
  __shared__ float wrow[HH];
  for (int i = tid; i < HH; i += 256) wrow[i] = Wv[e2 * HH + i];
  __syncthreads();
  for (int c = tid; c < HH; c += 256){
    float a = 0.f;
    for (int h2 = 0; h2 < HH; ++h2) a += wrow[h2] * projW[(size_t)h2 * HH + c];
    Acomb[(head * 4 + e2) * HH + c] = a;
  }
  int wv = tid >> 6, lane = tid & 63;
  if (wv == 0){
    float p = 0.f;
    for (int k = lane; k < HH; k += 64) p += wrow[k] * projb[k];
#pragma unroll
    for (int off = 32; off; off >>= 1) p += __shfl_down(p, off);
    if (lane == 0) Ccomb[head * 4 + e2] = p + bv[e2];
  }
}

// ---------------- fused expert heads: out = sum_e gate * (hcat.A_e + c_e) ----------------
__global__ __launch_bounds__(256) void k_heads(const short* __restrict__ hcat,
                                               const float* __restrict__ Acomb,
                                               const float* __restrict__ Ccomb,
                                               const float* __restrict__ gate,
                                               float* __restrict__ outp){
  __shared__ float Al[8 * HH];   // 24 KB
  int tid = threadIdx.x;
  for (int i = tid; i < 8 * HH; i += 256) Al[i] = Acomb[i];
  __syncthreads();
  int wv = tid >> 6, lane = tid & 63;
  int bw = blockIdx.x * 4 + wv;        // = b*512 + w
  const short* hr = hcat + (size_t)bw * HH;
  float hv[12];
#pragma unroll
  for (int j = 0; j < 12; ++j) hv[j] = bf2f(hr[lane + 64 * j]);
  float dsum[8];
#pragma unroll
  for (int v = 0; v < 8; ++v){
    float p = 0.f;
#pragma unroll
    for (int j = 0; j < 12; ++j) p += hv[j] * Al[v * HH + lane + 64 * j];
#pragma unroll
    for (int off = 32; off; off >>= 1) p += __shfl_xor(p, off);
    dsum[v] = p;
  }
  if (lane == 0){
    int b = bw >> 9;
    float fx = 0.f, du = 0.f;
#pragma unroll
    for (int e2 = 0; e2 < 4; ++e2){
      float g = gate[b * 4 + e2];
      fx += g * (dsum[e2]     + Ccomb[e2]);
      du += g * (dsum[4 + e2] + Ccomb[4 + e2]);
    }
    outp[bw] = fx;
    outp[BB * NW + bw] = du;
  }
}

extern "C" void kernel_launch(void* const* d_in, const int* in_sizes, int n_in,
                              void* d_out, int out_size, void* d_ws, size_t ws_size,
                              hipStream_t stream){
  const float* tok   = (const float*)d_in[0];
  const int*   wmap  = (const int*)d_in[1];
  const int*   lids  = (const int*)d_in[2];
  const float* Wih_f = (const float*)d_in[3];
  const float* Whh_f = (const float*)d_in[4];
  const float* bih_f = (const float*)d_in[5];
  const float* bhh_f = (const float*)d_in[6];
  const float* Wih_b = (const float*)d_in[7];
  const float* Whh_b = (const float*)d_in[8];
  const float* bih_b = (const float*)d_in[9];
  const float* bhh_b = (const float*)d_in[10];
  const float* projW = (const float*)d_in[11];
  const float* projb = (const float*)d_in[12];
  const float* ltab  = (const float*)d_in[13];
  const float* gW1   = (const float*)d_in[14];
  const float* gb1   = (const float*)d_in[15];
  const float* gW2   = (const float*)d_in[16];
  const float* gb2   = (const float*)d_in[17];
  const float* efW   = (const float*)d_in[18];
  const float* efb   = (const float*)d_in[19];
  const float* edW   = (const float*)d_in[20];
  const float* edb   = (const float*)d_in[21];
  float* outp = (float*)d_out;

  char* ws = (char*)d_ws;
  size_t off = 0;
  auto alloc = [&](size_t bytes) -> char* {
    char* p = ws + off;
    off = (off + bytes + 255) & ~(size_t)255;
    return p;
  };
  short* we_bf   = (short*)alloc((size_t)BB * NW * HH * 2);
  short* wihf_bf = (short*)alloc((size_t)G4 * HH * 2);
  short* wihb_bf = (short*)alloc((size_t)G4 * HH * 2);
  short* whhf_bf = (short*)alloc((size_t)G4 * HID * 2);
  short* whhb_bf = (short*)alloc((size_t)G4 * HID * 2);
  float* xg_f    = (float*)alloc((size_t)BB * NW * G4 * 4);
  float* xg_b    = (float*)alloc((size_t)BB * NW * G4 * 4);
  short* hcat    = (short*)alloc((size_t)BB * NW * HH * 2);
  short* hbuf    = (short*)alloc((size_t)2 * 2 * BB * HID * 2);
  int*   flags   = (int*)alloc((size_t)2 * NW * 4);
  float* gateb   = (float*)alloc((size_t)BB * EE * 4);
  float* Acomb   = (float*)alloc((size_t)8 * HH * 4);
  float* Ccomb   = (float*)alloc((size_t)8 * 4);

  k_zero<<<4, 256, 0, stream>>>(flags);
  k_f2bf<<<1024, 256, 0, stream>>>(Wih_f, wihf_bf, G4 * HH);
  k_f2bf<<<1024, 256, 0, stream>>>(Wih_b, wihb_bf, G4 * HH);
  k_f2bf<<<512, 256, 0, stream>>>(Whh_f, whhf_bf, G4 * HID);
  k_f2bf<<<512, 256, 0, stream>>>(Whh_b, whhb_bf, G4 * HID);
  k_segmean<<<BB * NW, 256, 0, stream>>>(tok, wmap, we_bf);
  k_gemm_bt<<<(BB * NW / 128) * (G4 / 128), 256, 0, stream>>>(we_bf, wihf_bf, bih_f, bhh_f, xg_f, BB * NW, G4, HH);
  k_gemm_bt<<<(BB * NW / 128) * (G4 / 128), 256, 0, stream>>>(we_bf, wihb_bf, bih_b, bhh_b, xg_b, BB * NW, G4, HH);
  k_gate<<<BB, 256, 0, stream>>>(tok, lids, ltab, gW1, gb1, gW2, gb2, gateb);
  k_headpre<<<8, 256, 0, stream>>>(efW, efb, edW, edb, projW, projb, Acomb, Ccomb);
  k_lstm<<<2 * CWG, 256, 0, stream>>>(xg_f, xg_b, whhf_bf, whhb_bf, hbuf, hcat, flags);
  k_heads<<<(BB * NW) / 4, 256, 0, stream>>>(hcat, Acomb, Ccomb, gateb, outp);
}

// Round 2
// 2321.810 us; speedup vs baseline: 2.9205x; 2.9205x over previous
//
#include <hip/hip_runtime.h>
#include <stdint.h>

#define BB 32
#define LL 1024
#define NW 512
#define HH 768
#define HID 384
#define G4 1536   // 4*HID
#define EE 4
#define DLL 128
#define GIN 896   // H+DL
#define CWG 12    // column-group WGs per direction
#define WGC 32    // h-cols per WG
#define HPAD 392  // padded LDS row stride (shorts), 16B aligned, breaks bank conflicts

typedef __attribute__((ext_vector_type(8))) short short8;
typedef __attribute__((ext_vector_type(4))) float f32x4;
typedef __attribute__((ext_vector_type(2))) float f32x2;

__device__ __forceinline__ float bf2f(short s){
  union { unsigned int u; float f; } v; v.u = ((unsigned int)(unsigned short)s) << 16; return v.f;
}
__device__ __forceinline__ short f2bf(float f){
  union { float f; unsigned int u; } v; v.f = f;
  unsigned int r = v.u + 0x7fffu + ((v.u >> 16) & 1u);
  return (short)(r >> 16);
}
__device__ __forceinline__ float sigm(float x){ return 1.f / (1.f + __expf(-x)); }

// ---------------- zero flags ----------------
__global__ void k_zero(int* flags){
  int i = blockIdx.x * 256 + threadIdx.x;
  if (i < 2 * NW) flags[i] = 0;
}

// ---------------- f32 -> bf16 convert ----------------
__global__ void k_f2bf(const float* in, short* out, int n){
  int i = blockIdx.x * blockDim.x + threadIdx.x;
  int st = gridDim.x * blockDim.x;
  for (; i < n; i += st) out[i] = f2bf(in[i]);
}

// ---------------- segment mean pooling ----------------
__global__ __launch_bounds__(256) void k_segmean(const float* __restrict__ tok,
                                                 const int* __restrict__ wmap,
                                                 short* __restrict__ we_bf){
  int blk = blockIdx.x;
  int b = blk >> 9;          // / NW
  int w = blk & 511;
  const int* m = wmap + b * LL;
  int lo = 0, hi = LL;
  while (lo < hi){ int mid = (lo + hi) >> 1; if (m[mid] < w) lo = mid + 1; else hi = mid; }
  int s = lo;
  int lo2 = s, hi2 = LL;
  while (lo2 < hi2){ int mid = (lo2 + hi2) >> 1; if (m[mid] <= w) lo2 = mid + 1; else hi2 = mid; }
  int e = lo2;
  float cnt = (float)(e - s);
  float denom = fmaxf(cnt, 1.f);
  for (int j = threadIdx.x; j < HH; j += 256){
    float acc = 0.f;
    for (int r = s; r < e; ++r) acc += tok[((size_t)b * LL + r) * HH + j];
    we_bf[((size_t)b * NW + w) * HH + j] = f2bf(acc / denom);
  }
}

// ---------------- GEMM: C[M,N] = A[M,K](bf16) * W[N,K]^T(bf16) + b1[n] + b2[n] ----------------
__global__ __launch_bounds__(256) void k_gemm_bt(const short* __restrict__ Abf,
                                                 const short* __restrict__ Wbf,
                                                 const float* __restrict__ b1,
                                                 const float* __restrict__ b2,
                                                 float* __restrict__ Cf,
                                                 int M, int N, int K){
  __shared__ __attribute__((aligned(16))) short As[128 * 32];
  __shared__ __attribute__((aligned(16))) short Bs[128 * 32];
  int ntiles = N >> 7;
  int m0 = (blockIdx.x / ntiles) << 7;
  int n0 = (blockIdx.x % ntiles) << 7;
  int tid = threadIdx.x, lane = tid & 63, wv = tid >> 6;
  int wm = (wv >> 1) << 6, wn = (wv & 1) << 6;
  f32x4 acc[4][4] = {};
  for (int kk = 0; kk < K; kk += 32){
#pragma unroll
    for (int q = 0; q < 2; ++q){
      int e = (q * 256 + tid) * 8;
      int row = e >> 5, col = e & 31;
      *(short8*)(As + e) = *(const short8*)(Abf + (size_t)(m0 + row) * K + kk + col);
      *(short8*)(Bs + e) = *(const short8*)(Wbf + (size_t)(n0 + row) * K + kk + col);
    }
    __syncthreads();
    short8 af[4], bfr[4];
#pragma unroll
    for (int x = 0; x < 4; ++x){
      af[x]  = *(const short8*)(As + (wm + x * 16 + (lane & 15)) * 32 + ((lane >> 4) << 3));
      bfr[x] = *(const short8*)(Bs + (wn + x * 16 + (lane & 15)) * 32 + ((lane >> 4) << 3));
    }
#pragma unroll
    for (int x = 0; x < 4; ++x)
#pragma unroll
      for (int y = 0; y < 4; ++y)
        acc[x][y] = __builtin_amdgcn_mfma_f32_16x16x32_bf16(af[x], bfr[y], acc[x][y], 0, 0, 0);
    __syncthreads();
  }
#pragma unroll
  for (int x = 0; x < 4; ++x)
#pragma unroll
    for (int y = 0; y < 4; ++y)
#pragma unroll
      for (int i = 0; i < 4; ++i){
        int mm = m0 + wm + x * 16 + ((lane >> 4) << 2) + i;
        int nn = n0 + wn + y * 16 + (lane & 15);
        Cf[(size_t)mm * N + nn] = acc[x][y][i] + b1[nn] + b2[nn];
      }
}

// ---------------- BiLSTM: persistent, relaxed-coherent flag sync, Whh resident ----------------
// 12 WGs/direction x 512 threads (8 waves). Wave wv: gate g=wv>>1, col-half nh=wv&1
// -> 16 gate-rows. All shared h/flag traffic via RELAXED agent atomics (sc0 sc1,
// point-to-point through MALL) — no buffer_wbl2 / buffer_inv on the critical path.
__global__ __launch_bounds__(512) void k_lstm(const float* __restrict__ xg_f,
                                              const float* __restrict__ xg_b,
                                              const short* __restrict__ whh_f,
                                              const short* __restrict__ whh_b,
                                              short* __restrict__ hbuf,
                                              short* __restrict__ hcat,
                                              int* __restrict__ flags){
  int bx = blockIdx.x;
  int dir = bx / CWG;
  int cg  = bx % CWG;
  int tid = threadIdx.x, lane = tid & 63, wv = tid >> 6;
  const float* xg  = dir ? xg_b : xg_f;
  const short* whh = dir ? whh_b : whh_f;
  int g  = wv >> 1;                    // gate (i,f,g,o)
  int nh = wv & 1;                     // 16-col half within WG's 32 cols
  int jbase = g * HID + cg * WGC + nh * 16;

  // resident Whh B-fragments: 16 gate-rows x K=384 -> 12 k-steps, 48 VGPRs
  short8 bfrag[12];
  {
    const short* wr = whh + (size_t)(jbase + (lane & 15)) * HID + ((lane >> 4) << 3);
#pragma unroll
    for (int ks = 0; ks < 12; ++ks) bfrag[ks] = *(const short8*)(wr + ks * 32);
  }

  __shared__ __attribute__((aligned(16))) short hs[32 * HPAD];  // staged h(t-1), 24.5 KB
  __shared__ float pre[4][BB][WGC];                             // gate preacts, 16 KB

  float c0 = 0.f, c1 = 0.f;
  int eb = tid >> 4, ecp = (tid & 15) * 2;   // elementwise (b, even col within WG)
  int crow = tid >> 4, cidx = tid & 15;      // h-copy: 16 threads per b-row, 48B each
  int* flg = flags + dir * NW;
  short* hb0 = hbuf + (size_t)dir * 2 * BB * HID;

  for (int t = 0; t < NW; ++t){
    int t_act = dir ? (NW - 1 - t) : t;
    // xg prefetch (independent of h) — overlaps flag wait
    float xgv[8];
#pragma unroll
    for (int mt = 0; mt < 2; ++mt)
#pragma unroll
      for (int i = 0; i < 4; ++i){
        int bb = mt * 16 + ((lane >> 4) << 2) + i;
        xgv[mt * 4 + i] = xg[((size_t)bb * NW + t_act) * G4 + jbase + (lane & 15)];
      }
    f32x4 acc0 = {}, acc1 = {};
    if (t > 0){
      if (tid == 0){
        while (__hip_atomic_load(&flg[t - 1], __ATOMIC_RELAXED, __HIP_MEMORY_SCOPE_AGENT) < CWG)
          __builtin_amdgcn_s_sleep(1);
      }
      __syncthreads();
      // stage h(t-1) -> LDS via per-access coherent loads (48 B/thread)
      const short* hp = hb0 + ((t - 1) & 1) * BB * HID;
      const unsigned long long* src = (const unsigned long long*)(hp + (size_t)crow * HID);
#pragma unroll
      for (int q = 0; q < 6; ++q){
        unsigned long long v = __hip_atomic_load(src + cidx * 6 + q,
                                                 __ATOMIC_RELAXED, __HIP_MEMORY_SCOPE_AGENT);
        *(unsigned long long*)(hs + crow * HPAD + cidx * 24 + q * 4) = v;
      }
      __syncthreads();
#pragma unroll
      for (int ks = 0; ks < 12; ++ks){
        short8 a0 = *(const short8*)(hs + (lane & 15) * HPAD        + ks * 32 + ((lane >> 4) << 3));
        short8 a1 = *(const short8*)(hs + ((lane & 15) + 16) * HPAD + ks * 32 + ((lane >> 4) << 3));
        acc0 = __builtin_amdgcn_mfma_f32_16x16x32_bf16(a0, bfrag[ks], acc0, 0, 0, 0);
        acc1 = __builtin_amdgcn_mfma_f32_16x16x32_bf16(a1, bfrag[ks], acc1, 0, 0, 0);
      }
    }
#pragma unroll
    for (int i = 0; i < 4; ++i){
      int b0 = ((lane >> 4) << 2) + i;
      pre[g][b0][nh * 16 + (lane & 15)]      = acc0[i] + xgv[i];
      pre[g][b0 + 16][nh * 16 + (lane & 15)] = acc1[i] + xgv[4 + i];
    }
    __syncthreads();
    // elementwise LSTM cell for (eb, ecp) and (eb, ecp+1)
    f32x2 gi = *(f32x2*)&pre[0][eb][ecp];
    f32x2 gf = *(f32x2*)&pre[1][eb][ecp];
    f32x2 gg = *(f32x2*)&pre[2][eb][ecp];
    f32x2 go = *(f32x2*)&pre[3][eb][ecp];
    c0 = sigm(gf.x) * c0 + sigm(gi.x) * tanhf(gg.x);
    float h0 = sigm(go.x) * tanhf(c0);
    c1 = sigm(gf.y) * c1 + sigm(gi.y) * tanhf(gg.y);
    float h1 = sigm(go.y) * tanhf(c1);
    unsigned int packed = (unsigned int)(unsigned short)f2bf(h0) |
                          ((unsigned int)(unsigned short)f2bf(h1) << 16);
    short* hw = hb0 + (t & 1) * BB * HID;
    __hip_atomic_store((unsigned int*)(hw + eb * HID + cg * WGC + ecp), packed,
                       __ATOMIC_RELAXED, __HIP_MEMORY_SCOPE_AGENT);
    *(unsigned int*)(hcat + ((size_t)eb * NW + t_act) * HH + dir * HID + cg * WGC + ecp) = packed;
    // h stores (sc1) ack'd at coherence point before flag bump
    asm volatile("s_waitcnt vmcnt(0)" ::: "memory");
    __syncthreads();
    if (tid == 0)
      __hip_atomic_fetch_add(&flg[t], 1, __ATOMIC_RELAXED, __HIP_MEMORY_SCOPE_AGENT);
  }
}

// ---------------- gate MLP + softmax (per batch row) ----------------
__global__ __launch_bounds__(256) void k_gate(const float* __restrict__ tok,
                                              const int* __restrict__ lids,
                                              const float* __restrict__ ltab,
                                              const float* __restrict__ W1,
                                              const float* __restrict__ b1v,
                                              const float* __restrict__ W2,
                                              const float* __restrict__ b2v,
                                              float* __restrict__ gate){
  __shared__ float gin[GIN];
  __shared__ float hid[HH];
  __shared__ float pr[EE];
  int b = blockIdx.x, tid = threadIdx.x;
  int lid = lids[b];
  for (int i = tid; i < GIN; i += 256)
    gin[i] = (i < HH) ? tok[(size_t)b * LL * HH + i] : ltab[lid * DLL + (i - HH)];
  __syncthreads();
  for (int j = tid; j < HH; j += 256){
    float a = b1v[j];
    const float* wr = W1 + (size_t)j * GIN;
    for (int k = 0; k < GIN; ++k) a += gin[k] * wr[k];
    hid[j] = fmaxf(a, 0.f);
  }
  __syncthreads();
  int wv = tid >> 6, lane = tid & 63;
  if (wv < EE){
    float p = 0.f;
    for (int k = lane; k < HH; k += 64) p += hid[k] * W2[wv * HH + k];
#pragma unroll
    for (int off = 32; off; off >>= 1) p += __shfl_down(p, off);
    if (lane == 0) pr[wv] = p + b2v[wv];
  }
  __syncthreads();
  if (tid == 0){
    float mx = fmaxf(fmaxf(pr[0], pr[1]), fmaxf(pr[2], pr[3]));
    float s = 0.f, ex[EE];
    for (int e2 = 0; e2 < EE; ++e2){ ex[e2] = __expf(pr[e2] - mx); s += ex[e2]; }
    for (int e2 = 0; e2 < EE; ++e2) gate[b * EE + e2] = ex[e2] / s;
  }
}

// ---------------- head precompute: A = headW @ proj_W, c = headW.proj_b + head_b ----------------
__global__ __launch_bounds__(256) void k_headpre(const float* __restrict__ efW,
                                                 const float* __restrict__ efb,
                                                 const float* __restrict__ edW,
                                                 const float* __restrict__ edb,
                                                 const float* __restrict__ projW,
                                                 const float* __restrict__ projb,
                                                 float* __restrict__ Acomb,
                                                 float* __restrict__ Ccomb){
  int head = blockIdx.x >> 2, e2 = blockIdx.x & 3, tid = threadIdx.x;
  const float* Wv = head ? edW : efW;
  const float* bv = head ? edb : efb;
  __shared__ float wrow[HH];
  for (int i = tid; i < HH; i += 256) wrow[i] = Wv[e2 * HH + i];
  __syncthreads();
  for (int c = tid; c < HH; c += 256){
    float a = 0.f;
    for (int h2 = 0; h2 < HH; ++h2) a += wrow[h2] * projW[(size_t)h2 * HH + c];
    Acomb[(head * 4 + e2) * HH + c] = a;
  }
  int wv = tid >> 6, lane = tid & 63;
  if (wv == 0){
    float p = 0.f;
    for (int k = lane; k < HH; k += 64) p += wrow[k] * projb[k];
#pragma unroll
    for (int off = 32; off; off >>= 1) p += __shfl_down(p, off);
    if (lane == 0) Ccomb[head * 4 + e2] = p + bv[e2];
  }
}

// ---------------- fused expert heads: out = sum_e gate * (hcat.A_e + c_e) ----------------
__global__ __launch_bounds__(256) void k_heads(const short* __restrict__ hcat,
                                               const float* __restrict__ Acomb,
                                               const float* __restrict__ Ccomb,
                                               const float* __restrict__ gate,
                                               float* __restrict__ outp){
  __shared__ float Al[8 * HH];   // 24 KB
  int tid = threadIdx.x;
  for (int i = tid; i < 8 * HH; i += 256) Al[i] = Acomb[i];
  __syncthreads();
  int wv = tid >> 6, lane = tid & 63;
  int bw = blockIdx.x * 4 + wv;        // = b*512 + w
  const short* hr = hcat + (size_t)bw * HH;
  float hv[12];
#pragma unroll
  for (int j = 0; j < 12; ++j) hv[j] = bf2f(hr[lane + 64 * j]);
  float dsum[8];
#pragma unroll
  for (int v = 0; v < 8; ++v){
    float p = 0.f;
#pragma unroll
    for (int j = 0; j < 12; ++j) p += hv[j] * Al[v * HH + lane + 64 * j];
#pragma unroll
    for (int off = 32; off; off >>= 1) p += __shfl_xor(p, off);
    dsum[v] = p;
  }
  if (lane == 0){
    int b = bw >> 9;
    float fx = 0.f, du = 0.f;
#pragma unroll
    for (int e2 = 0; e2 < 4; ++e2){
      float g = gate[b * 4 + e2];
      fx += g * (dsum[e2]     + Ccomb[e2]);
      du += g * (dsum[4 + e2] + Ccomb[4 + e2]);
    }
    outp[bw] = fx;
    outp[BB * NW + bw] = du;
  }
}

extern "C" void kernel_launch(void* const* d_in, const int* in_sizes, int n_in,
                              void* d_out, int out_size, void* d_ws, size_t ws_size,
                              hipStream_t stream){
  const float* tok   = (const float*)d_in[0];
  const int*   wmap  = (const int*)d_in[1];
  const int*   lids  = (const int*)d_in[2];
  const float* Wih_f = (const float*)d_in[3];
  const float* Whh_f = (const float*)d_in[4];
  const float* bih_f = (const float*)d_in[5];
  const float* bhh_f = (const float*)d_in[6];
  const float* Wih_b = (const float*)d_in[7];
  const float* Whh_b = (const float*)d_in[8];
  const float* bih_b = (const float*)d_in[9];
  const float* bhh_b = (const float*)d_in[10];
  const float* projW = (const float*)d_in[11];
  const float* projb = (const float*)d_in[12];
  const float* ltab  = (const float*)d_in[13];
  const float* gW1   = (const float*)d_in[14];
  const float* gb1   = (const float*)d_in[15];
  const float* gW2   = (const float*)d_in[16];
  const float* gb2   = (const float*)d_in[17];
  const float* efW   = (const float*)d_in[18];
  const float* efb   = (const float*)d_in[19];
  const float* edW   = (const float*)d_in[20];
  const float* edb   = (const float*)d_in[21];
  float* outp = (float*)d_out;

  char* ws = (char*)d_ws;
  size_t off = 0;
  auto alloc = [&](size_t bytes) -> char* {
    char* p = ws + off;
    off = (off + bytes + 255) & ~(size_t)255;
    return p;
  };
  short* we_bf   = (short*)alloc((size_t)BB * NW * HH * 2);
  short* wihf_bf = (short*)alloc((size_t)G4 * HH * 2);
  short* wihb_bf = (short*)alloc((size_t)G4 * HH * 2);
  short* whhf_bf = (short*)alloc((size_t)G4 * HID * 2);
  short* whhb_bf = (short*)alloc((size_t)G4 * HID * 2);
  float* xg_f    = (float*)alloc((size_t)BB * NW * G4 * 4);
  float* xg_b    = (float*)alloc((size_t)BB * NW * G4 * 4);
  short* hcat    = (short*)alloc((size_t)BB * NW * HH * 2);
  short* hbuf    = (short*)alloc((size_t)2 * 2 * BB * HID * 2);
  int*   flags   = (int*)alloc((size_t)2 * NW * 4);
  float* gateb   = (float*)alloc((size_t)BB * EE * 4);
  float* Acomb   = (float*)alloc((size_t)8 * HH * 4);
  float* Ccomb   = (float*)alloc((size_t)8 * 4);

  k_zero<<<4, 256, 0, stream>>>(flags);
  k_f2bf<<<1024, 256, 0, stream>>>(Wih_f, wihf_bf, G4 * HH);
  k_f2bf<<<1024, 256, 0, stream>>>(Wih_b, wihb_bf, G4 * HH);
  k_f2bf<<<512, 256, 0, stream>>>(Whh_f, whhf_bf, G4 * HID);
  k_f2bf<<<512, 256, 0, stream>>>(Whh_b, whhb_bf, G4 * HID);
  k_segmean<<<BB * NW, 256, 0, stream>>>(tok, wmap, we_bf);
  k_gemm_bt<<<(BB * NW / 128) * (G4 / 128), 256, 0, stream>>>(we_bf, wihf_bf, bih_f, bhh_f, xg_f, BB * NW, G4, HH);
  k_gemm_bt<<<(BB * NW / 128) * (G4 / 128), 256, 0, stream>>>(we_bf, wihb_bf, bih_b, bhh_b, xg_b, BB * NW, G4, HH);
  k_gate<<<BB, 256, 0, stream>>>(tok, lids, ltab, gW1, gb1, gW2, gb2, gateb);
  k_headpre<<<8, 256, 0, stream>>>(efW, efb, edW, edb, projW, projb, Acomb, Ccomb);
  k_lstm<<<2 * CWG, 512, 0, stream>>>(xg_f, xg_b, whhf_bf, whhb_bf, hbuf, hcat, flags);
  k_heads<<<(BB * NW) / 4, 256, 0, stream>>>(hcat, Acomb, Ccomb, gateb, outp);
}

// Round 3
// 2176.156 us; speedup vs baseline: 3.1160x; 1.0669x over previous
//
#include <hip/hip_runtime.h>
#include <stdint.h>

#define BB 32
#define LL 1024
#define NW 512
#define HH 768
#define HID 384
#define G4 1536   // 4*HID
#define EE 4
#define DLL 128
#define GIN 896   // H+DL
#define CWG 12    // column-group WGs per direction
#define WGC 32    // h-cols per WG
#define HPAD 392  // padded LDS row stride (shorts): 784B, 16B-aligned, 2-way max on b128

typedef __attribute__((ext_vector_type(8))) short short8;
typedef __attribute__((ext_vector_type(4))) float f32x4;
typedef __attribute__((ext_vector_type(2))) float f32x2;

__device__ __forceinline__ float bf2f(short s){
  union { unsigned int u; float f; } v; v.u = ((unsigned int)(unsigned short)s) << 16; return v.f;
}
__device__ __forceinline__ short f2bf(float f){
  union { float f; unsigned int u; } v; v.f = f;
  unsigned int r = v.u + 0x7fffu + ((v.u >> 16) & 1u);
  return (short)(r >> 16);
}
__device__ __forceinline__ float sigm(float x){ return 1.f / (1.f + __expf(-x)); }

__device__ __forceinline__ void gload16(const void* g, void* l){
  __builtin_amdgcn_global_load_lds(
      (const __attribute__((address_space(1))) unsigned int*)g,
      (__attribute__((address_space(3))) unsigned int*)l, 16, 0, 0);
}

// ---------------- zero flags ----------------
__global__ void k_zero(int* flags, int n){
  int i = blockIdx.x * 256 + threadIdx.x;
  if (i < n) flags[i] = 0;
}

// ---------------- f32 -> bf16 convert ----------------
__global__ void k_f2bf(const float* in, short* out, int n){
  int i = blockIdx.x * blockDim.x + threadIdx.x;
  int st = gridDim.x * blockDim.x;
  for (; i < n; i += st) out[i] = f2bf(in[i]);
}

// ---------------- segment mean pooling ----------------
__global__ __launch_bounds__(256) void k_segmean(const float* __restrict__ tok,
                                                 const int* __restrict__ wmap,
                                                 short* __restrict__ we_bf){
  int blk = blockIdx.x;
  int b = blk >> 9;          // / NW
  int w = blk & 511;
  const int* m = wmap + b * LL;
  int lo = 0, hi = LL;
  while (lo < hi){ int mid = (lo + hi) >> 1; if (m[mid] < w) lo = mid + 1; else hi = mid; }
  int s = lo;
  int lo2 = s, hi2 = LL;
  while (lo2 < hi2){ int mid = (lo2 + hi2) >> 1; if (m[mid] <= w) lo2 = mid + 1; else hi2 = mid; }
  int e = lo2;
  float cnt = (float)(e - s);
  float denom = fmaxf(cnt, 1.f);
  for (int j = threadIdx.x; j < HH; j += 256){
    float acc = 0.f;
    for (int r = s; r < e; ++r) acc += tok[((size_t)b * LL + r) * HH + j];
    we_bf[((size_t)b * NW + w) * HH + j] = f2bf(acc / denom);
  }
}

// ---------------- GEMM: C[M,N] = A[M,K](bf16) * W[N,K]^T(bf16) + b1[n] + b2[n] ----------------
__global__ __launch_bounds__(256) void k_gemm_bt(const short* __restrict__ Abf,
                                                 const short* __restrict__ Wbf,
                                                 const float* __restrict__ b1,
                                                 const float* __restrict__ b2,
                                                 float* __restrict__ Cf,
                                                 int M, int N, int K){
  __shared__ __attribute__((aligned(16))) short As[128 * 32];
  __shared__ __attribute__((aligned(16))) short Bs[128 * 32];
  int ntiles = N >> 7;
  int m0 = (blockIdx.x / ntiles) << 7;
  int n0 = (blockIdx.x % ntiles) << 7;
  int tid = threadIdx.x, lane = tid & 63, wv = tid >> 6;
  int wm = (wv >> 1) << 6, wn = (wv & 1) << 6;
  f32x4 acc[4][4] = {};
  for (int kk = 0; kk < K; kk += 32){
#pragma unroll
    for (int q = 0; q < 2; ++q){
      int e = q * 256 + tid;        // 16B granule: row = e/4, col = (e&3)*8 shorts
      int row = e >> 2, col = (e & 3) << 3;
      gload16(Abf + (size_t)(m0 + row) * K + kk + col, As + e * 8);
      gload16(Wbf + (size_t)(n0 + row) * K + kk + col, Bs + e * 8);
    }
    __syncthreads();   // drains vmcnt (incl. global_load_lds)
    short8 af[4], bfr[4];
#pragma unroll
    for (int x = 0; x < 4; ++x){
      af[x]  = *(const short8*)(As + (wm + x * 16 + (lane & 15)) * 32 + ((lane >> 4) << 3));
      bfr[x] = *(const short8*)(Bs + (wn + x * 16 + (lane & 15)) * 32 + ((lane >> 4) << 3));
    }
#pragma unroll
    for (int x = 0; x < 4; ++x)
#pragma unroll
      for (int y = 0; y < 4; ++y)
        acc[x][y] = __builtin_amdgcn_mfma_f32_16x16x32_bf16(af[x], bfr[y], acc[x][y], 0, 0, 0);
    __syncthreads();
  }
#pragma unroll
  for (int x = 0; x < 4; ++x)
#pragma unroll
    for (int y = 0; y < 4; ++y)
#pragma unroll
      for (int i = 0; i < 4; ++i){
        int mm = m0 + wm + x * 16 + ((lane >> 4) << 2) + i;
        int nn = n0 + wn + y * 16 + (lane & 15);
        Cf[(size_t)mm * N + nn] = acc[x][y][i] + b1[nn] + b2[nn];
      }
}

// ---------------- BiLSTM: persistent, per-cg store-flags, coalesced coherent staging ----------------
// 12 WGs/direction x 512 threads (8 waves). Wave wv: gate g=wv>>1, col-half nh=wv&1.
__global__ __launch_bounds__(512) void k_lstm(const float* __restrict__ xg_f,
                                              const float* __restrict__ xg_b,
                                              const short* __restrict__ whh_f,
                                              const short* __restrict__ whh_b,
                                              short* __restrict__ hbuf,
                                              short* __restrict__ hcat,
                                              int* __restrict__ flags){
  int bx = blockIdx.x;
  int dir = bx / CWG;
  int cg  = bx % CWG;
  int tid = threadIdx.x, lane = tid & 63, wv = tid >> 6;
  const float* xg  = dir ? xg_b : xg_f;
  const short* whh = dir ? whh_b : whh_f;
  int g  = wv >> 1;                    // gate (i,f,g,o)
  int nh = wv & 1;                     // 16-col half within WG's 32 cols
  int jbase = g * HID + cg * WGC + nh * 16;

  // resident Whh B-fragments: 16 gate-rows x K=384 -> 12 k-steps, 48 VGPRs
  short8 bfrag[12];
  {
    const short* wr = whh + (size_t)(jbase + (lane & 15)) * HID + ((lane >> 4) << 3);
#pragma unroll
    for (int ks = 0; ks < 12; ++ks) bfrag[ks] = *(const short8*)(wr + ks * 32);
  }

  __shared__ __attribute__((aligned(16))) short hs[32 * HPAD];  // staged h(t-1), 24.5 KB
  __shared__ float pre[4][BB][36];     // padded: 4*b0+col -> 32 distinct banks, conflict-free

  float c0 = 0.f, c1 = 0.f;
  int eb = tid >> 4, ecp = (tid & 15) * 2;   // elementwise (b, even col within WG)
  int pc = lane & 15;                        // poll lane index
  int* flgD = flags + dir * NW * 16;
  short* hb0 = hbuf + (size_t)dir * 2 * BB * HID;

  for (int t = 0; t < NW; ++t){
    int t_act = dir ? (NW - 1 - t) : t;
    // xg prefetch (independent of h) — overlaps flag wait
    float xgv[8];
#pragma unroll
    for (int mt = 0; mt < 2; ++mt)
#pragma unroll
      for (int i = 0; i < 4; ++i){
        int bb = mt * 16 + ((lane >> 4) << 2) + i;
        xgv[mt * 4 + i] = xg[((size_t)bb * NW + t_act) * G4 + jbase + (lane & 15)];
      }
    f32x4 acc0 = {}, acc1 = {};
    if (t > 0){
      // all-wave ballot poll on the 12 per-cg flags (one 64B line)
      const int* fl = flgD + (t - 1) * 16;
      for (;;){
        int v = __hip_atomic_load(&fl[pc], __ATOMIC_RELAXED, __HIP_MEMORY_SCOPE_AGENT);
        if (__all(v != 0 || pc >= CWG)) break;
      }
      // stage h(t-1) -> LDS, coalesced: 3 x b128 coherent loads per thread
      const short* hp = hb0 + ((t - 1) & 1) * BB * HID;
      short8 sv0, sv1, sv2;
      {
        const short* s0 = hp + (0 * 512 + tid) * 8;
        const short* s1 = hp + (1 * 512 + tid) * 8;
        const short* s2 = hp + (2 * 512 + tid) * 8;
        asm volatile("global_load_dwordx4 %0, %1, off sc0 sc1" : "=v"(sv0) : "v"(s0) : "memory");
        asm volatile("global_load_dwordx4 %0, %1, off sc0 sc1" : "=v"(sv1) : "v"(s1) : "memory");
        asm volatile("global_load_dwordx4 %0, %1, off sc0 sc1" : "=v"(sv2) : "v"(s2) : "memory");
        asm volatile("s_waitcnt vmcnt(0)" ::: "memory");
      }
      short8 svv[3] = {sv0, sv1, sv2};
#pragma unroll
      for (int q = 0; q < 3; ++q){
        int gi = q * 512 + tid;
        int b = gi / 48, rem = gi % 48;
        *(short8*)(hs + b * HPAD + rem * 8) = svv[q];
      }
      if (cg == 0){
        // stager writes hcat for step t-1 from its registers (off producers' path)
        int tprev = dir ? (NW - t) : (t - 1);
#pragma unroll
        for (int q = 0; q < 3; ++q){
          int gi = q * 512 + tid;
          int b = gi / 48, rem = gi % 48;
          *(short8*)(hcat + ((size_t)b * NW + tprev) * HH + dir * HID + rem * 8) = svv[q];
        }
      }
      __syncthreads();   // barrier A: staging complete
#pragma unroll
      for (int ks = 0; ks < 12; ++ks){
        short8 a0 = *(const short8*)(hs + (lane & 15) * HPAD        + ks * 32 + ((lane >> 4) << 3));
        short8 a1 = *(const short8*)(hs + ((lane & 15) + 16) * HPAD + ks * 32 + ((lane >> 4) << 3));
        acc0 = __builtin_amdgcn_mfma_f32_16x16x32_bf16(a0, bfrag[ks], acc0, 0, 0, 0);
        acc1 = __builtin_amdgcn_mfma_f32_16x16x32_bf16(a1, bfrag[ks], acc1, 0, 0, 0);
      }
    }
#pragma unroll
    for (int i = 0; i < 4; ++i){
      int b0 = ((lane >> 4) << 2) + i;
      pre[g][b0][nh * 16 + (lane & 15)]      = acc0[i] + xgv[i];
      pre[g][b0 + 16][nh * 16 + (lane & 15)] = acc1[i] + xgv[4 + i];
    }
    __syncthreads();   // barrier B: preacts ready
    f32x2 gi2 = *(f32x2*)&pre[0][eb][ecp];
    f32x2 gf2 = *(f32x2*)&pre[1][eb][ecp];
    f32x2 gg2 = *(f32x2*)&pre[2][eb][ecp];
    f32x2 go2 = *(f32x2*)&pre[3][eb][ecp];
    c0 = sigm(gf2.x) * c0 + sigm(gi2.x) * tanhf(gg2.x);
    float h0 = sigm(go2.x) * tanhf(c0);
    c1 = sigm(gf2.y) * c1 + sigm(gi2.y) * tanhf(gg2.y);
    float h1 = sigm(go2.y) * tanhf(c1);
    unsigned int packed = (unsigned int)(unsigned short)f2bf(h0) |
                          ((unsigned int)(unsigned short)f2bf(h1) << 16);
    short* hw = hb0 + (t & 1) * BB * HID;
    __hip_atomic_store((unsigned int*)(hw + eb * HID + cg * WGC + ecp), packed,
                       __ATOMIC_RELAXED, __HIP_MEMORY_SCOPE_AGENT);
    if (t == NW - 1)   // final step's h never staged by anyone — producers write hcat
      *(unsigned int*)(hcat + ((size_t)eb * NW + t_act) * HH + dir * HID + cg * WGC + ecp) = packed;
    asm volatile("s_waitcnt vmcnt(0)" ::: "memory");  // h stores ack'd at coherence point
    __syncthreads();   // barrier C: all threads' stores ack'd
    if (tid == 0)
      __hip_atomic_store(&flgD[t * 16 + cg], 1, __ATOMIC_RELAXED, __HIP_MEMORY_SCOPE_AGENT);
  }
}

// ---------------- gate MLP + softmax (per batch row) ----------------
__global__ __launch_bounds__(256) void k_gate(const float* __restrict__ tok,
                                              const int* __restrict__ lids,
                                              const float* __restrict__ ltab,
                                              const float* __restrict__ W1,
                                              const float* __restrict__ b1v,
                                              const float* __restrict__ W2,
                                              const float* __restrict__ b2v,
                                              float* __restrict__ gate){
  __shared__ float gin[GIN];
  __shared__ float hid[HH];
  __shared__ float pr[EE];
  int b = blockIdx.x, tid = threadIdx.x;
  int lid = lids[b];
  for (int i = tid; i < GIN; i += 256)
    gin[i] = (i < HH) ? tok[(size_t)b * LL * HH + i] : ltab[lid * DLL + (i - HH)];
  __syncthreads();
  for (int j = tid; j < HH; j += 256){
    float a = b1v[j];
    const float* wr = W1 + (size_t)j * GIN;
    for (int k = 0; k < GIN; ++k) a += gin[k] * wr[k];
    hid[j] = fmaxf(a, 0.f);
  }
  __syncthreads();
  int wv = tid >> 6, lane = tid & 63;
  if (wv < EE){
    float p = 0.f;
    for (int k = lane; k < HH; k += 64) p += hid[k] * W2[wv * HH + k];
#pragma unroll
    for (int off = 32; off; off >>= 1) p += __shfl_down(p, off);
    if (lane == 0) pr[wv] = p + b2v[wv];
  }
  __syncthreads();
  if (tid == 0){
    float mx = fmaxf(fmaxf(pr[0], pr[1]), fmaxf(pr[2], pr[3]));
    float s = 0.f, ex[EE];
    for (int e2 = 0; e2 < EE; ++e2){ ex[e2] = __expf(pr[e2] - mx); s += ex[e2]; }
    for (int e2 = 0; e2 < EE; ++e2) gate[b * EE + e2] = ex[e2] / s;
  }
}

// ---------------- head precompute: A = headW @ proj_W, c = headW.proj_b + head_b ----------------
__global__ __launch_bounds__(256) void k_headpre(const float* __restrict__ efW,
                                                 const float* __restrict__ efb,
                                                 const float* __restrict__ edW,
                                                 const float* __restrict__ edb,
                                                 const float* __restrict__ projW,
                                                 const float* __restrict__ projb,
                                                 float* __restrict__ Acomb,
                                                 float* __restrict__ Ccomb){
  int head = blockIdx.x >> 2, e2 = blockIdx.x & 3, tid = threadIdx.x;
  const float* Wv = head ? edW : efW;
  const float* bv = head ? edb : efb;
  __shared__ float wrow[HH];
  for (int i = tid; i < HH; i += 256) wrow[i] = Wv[e2 * HH + i];
  __syncthreads();
  for (int c = tid; c < HH; c += 256){
    float a = 0.f;
    for (int h2 = 0; h2 < HH; ++h2) a += wrow[h2] * projW[(size_t)h2 * HH + c];
    Acomb[(head * 4 + e2) * HH + c] = a;
  }
  int wv = tid >> 6, lane = tid & 63;
  if (wv == 0){
    float p = 0.f;
    for (int k = lane; k < HH; k += 64) p += wrow[k] * projb[k];
#pragma unroll
    for (int off = 32; off; off >>= 1) p += __shfl_down(p, off);
    if (lane == 0) Ccomb[head * 4 + e2] = p + bv[e2];
  }
}

// ---------------- fused expert heads: out = sum_e gate * (hcat.A_e + c_e) ----------------
__global__ __launch_bounds__(256) void k_heads(const short* __restrict__ hcat,
                                               const float* __restrict__ Acomb,
                                               const float* __restrict__ Ccomb,
                                               const float* __restrict__ gate,
                                               float* __restrict__ outp){
  __shared__ float Al[8 * HH];   // 24 KB
  int tid = threadIdx.x;
  for (int i = tid; i < 8 * HH; i += 256) Al[i] = Acomb[i];
  __syncthreads();
  int wv = tid >> 6, lane = tid & 63;
  int bw = blockIdx.x * 4 + wv;        // = b*512 + w
  const short* hr = hcat + (size_t)bw * HH;
  float hv[12];
#pragma unroll
  for (int j = 0; j < 12; ++j) hv[j] = bf2f(hr[lane + 64 * j]);
  float dsum[8];
#pragma unroll
  for (int v = 0; v < 8; ++v){
    float p = 0.f;
#pragma unroll
    for (int j = 0; j < 12; ++j) p += hv[j] * Al[v * HH + lane + 64 * j];
#pragma unroll
    for (int off = 32; off; off >>= 1) p += __shfl_xor(p, off);
    dsum[v] = p;
  }
  if (lane == 0){
    int b = bw >> 9;
    float fx = 0.f, du = 0.f;
#pragma unroll
    for (int e2 = 0; e2 < 4; ++e2){
      float g = gate[b * 4 + e2];
      fx += g * (dsum[e2]     + Ccomb[e2]);
      du += g * (dsum[4 + e2] + Ccomb[4 + e2]);
    }
    outp[bw] = fx;
    outp[BB * NW + bw] = du;
  }
}

extern "C" void kernel_launch(void* const* d_in, const int* in_sizes, int n_in,
                              void* d_out, int out_size, void* d_ws, size_t ws_size,
                              hipStream_t stream){
  const float* tok   = (const float*)d_in[0];
  const int*   wmap  = (const int*)d_in[1];
  const int*   lids  = (const int*)d_in[2];
  const float* Wih_f = (const float*)d_in[3];
  const float* Whh_f = (const float*)d_in[4];
  const float* bih_f = (const float*)d_in[5];
  const float* bhh_f = (const float*)d_in[6];
  const float* Wih_b = (const float*)d_in[7];
  const float* Whh_b = (const float*)d_in[8];
  const float* bih_b = (const float*)d_in[9];
  const float* bhh_b = (const float*)d_in[10];
  const float* projW = (const float*)d_in[11];
  const float* projb = (const float*)d_in[12];
  const float* ltab  = (const float*)d_in[13];
  const float* gW1   = (const float*)d_in[14];
  const float* gb1   = (const float*)d_in[15];
  const float* gW2   = (const float*)d_in[16];
  const float* gb2   = (const float*)d_in[17];
  const float* efW   = (const float*)d_in[18];
  const float* efb   = (const float*)d_in[19];
  const float* edW   = (const float*)d_in[20];
  const float* edb   = (const float*)d_in[21];
  float* outp = (float*)d_out;

  char* ws = (char*)d_ws;
  size_t off = 0;
  auto alloc = [&](size_t bytes) -> char* {
    char* p = ws + off;
    off = (off + bytes + 255) & ~(size_t)255;
    return p;
  };
  short* we_bf   = (short*)alloc((size_t)BB * NW * HH * 2);
  short* wihf_bf = (short*)alloc((size_t)G4 * HH * 2);
  short* wihb_bf = (short*)alloc((size_t)G4 * HH * 2);
  short* whhf_bf = (short*)alloc((size_t)G4 * HID * 2);
  short* whhb_bf = (short*)alloc((size_t)G4 * HID * 2);
  float* xg_f    = (float*)alloc((size_t)BB * NW * G4 * 4);
  float* xg_b    = (float*)alloc((size_t)BB * NW * G4 * 4);
  short* hcat    = (short*)alloc((size_t)BB * NW * HH * 2);
  short* hbuf    = (short*)alloc((size_t)2 * 2 * BB * HID * 2);
  int*   flags   = (int*)alloc((size_t)2 * NW * 16 * 4);
  float* gateb   = (float*)alloc((size_t)BB * EE * 4);
  float* Acomb   = (float*)alloc((size_t)8 * HH * 4);
  float* Ccomb   = (float*)alloc((size_t)8 * 4);

  k_zero<<<(2 * NW * 16 + 255) / 256, 256, 0, stream>>>(flags, 2 * NW * 16);
  k_f2bf<<<1024, 256, 0, stream>>>(Wih_f, wihf_bf, G4 * HH);
  k_f2bf<<<1024, 256, 0, stream>>>(Wih_b, wihb_bf, G4 * HH);
  k_f2bf<<<512, 256, 0, stream>>>(Whh_f, whhf_bf, G4 * HID);
  k_f2bf<<<512, 256, 0, stream>>>(Whh_b, whhb_bf, G4 * HID);
  k_segmean<<<BB * NW, 256, 0, stream>>>(tok, wmap, we_bf);
  k_gemm_bt<<<(BB * NW / 128) * (G4 / 128), 256, 0, stream>>>(we_bf, wihf_bf, bih_f, bhh_f, xg_f, BB * NW, G4, HH);
  k_gemm_bt<<<(BB * NW / 128) * (G4 / 128), 256, 0, stream>>>(we_bf, wihb_bf, bih_b, bhh_b, xg_b, BB * NW, G4, HH);
  k_gate<<<BB, 256, 0, stream>>>(tok, lids, ltab, gW1, gb1, gW2, gb2, gateb);
  k_headpre<<<8, 256, 0, stream>>>(efW, efb, edW, edb, projW, projb, Acomb, Ccomb);
  k_lstm<<<2 * CWG, 512, 0, stream>>>(xg_f, xg_b, whhf_bf, whhb_bf, hbuf, hcat, flags);
  k_heads<<<(BB * NW) / 4, 256, 0, stream>>>(hcat, Acomb, Ccomb, gateb, outp);
}